// Round 15
// baseline (269.652 us; speedup 1.0000x reference)
//
#include <hip/hip_runtime.h>
#include <hip/hip_bf16.h>

// clusterLayer: q = rownorm( 1 / (1 + ||x||^2 + ||c||^2 - 2 x.cT) )
// N=524288, K=256, D=256. fp32 in/out.
// r15: K-chunked staging pipeline (fix bursty per-block HBM issue).
//   - K split into 4 chunks of 64. LDS double-buffers TWO chunks
//     (2 x 8 KiB). Chunk kc+1 is converted+written between MFMA steps
//     1 and 2 of chunk kc; chunk kc+2's global loads issued at top of
//     chunk kc -> each block issues HBM loads in 4 evenly spaced slots
//     across the K-loop (continuous per-CU HBM issue), instead of one
//     up-front burst (the ~50% duty ceiling of r7-r14).
//   - Swapped MFMA + simplified aug (r14): clusters stored -2c, aug frag
//     limbs3(1+|c|^2), constant ctx-aug [1,1,1]; x2 folded as scalar in
//     pass 1. In-lane row sums; dwordx4 stores straight from acc.
//   - 512 thr = 8 waves; BM=64; LDS ~20 KiB; launch_bounds(512,6):
//     ~84 regs, 6 waves/SIMD, 3 blocks/CU (r13 residency kept).

#define DD 256
#define KC 256
#define BM 64

typedef __attribute__((ext_vector_type(4)))  float f32x4;
typedef __attribute__((ext_vector_type(16))) float f32x16;
typedef __attribute__((ext_vector_type(8)))  short bf16x8;
typedef __attribute__((ext_vector_type(4)))  short bf16x4;
typedef __attribute__((ext_vector_type(4)))  unsigned u32x4;

__device__ __forceinline__ short f2bf(float f) {
    union { float f; unsigned u; } v; v.f = f;
    unsigned r = (v.u + 0x7fffu + ((v.u >> 16) & 1u)) >> 16;
    return (short)r;
}

__device__ __forceinline__ float bf2f(short h) {
    return __builtin_bit_cast(float, ((unsigned)(unsigned short)h) << 16);
}

__device__ __forceinline__ unsigned cvtpk(float a, float b) {
    unsigned r;
    asm("v_cvt_pk_bf16_f32 %0, %1, %2" : "=v"(r) : "v"(a), "v"(b));
    return r;
}

__device__ __forceinline__ float frcp(float x) {
    return __builtin_amdgcn_rcpf(x);
}

__device__ __forceinline__ f32x4 ld4(const float* p) { return *(const f32x4*)p; }

// ---------------- Kernel 0: prep clusters (unchanged from r14) ----------------
__global__ __launch_bounds__(64)
void prep_clusters(const float* __restrict__ clus, short* __restrict__ wsb) {
    const int c = blockIdx.x;      // cluster row 0..255
    const int t = threadIdx.x;     // 0..63, 4 floats each
    f32x4 v = *(const f32x4*)(clus + c * DD + t * 4);
    bf16x4 o;
    o[0] = f2bf(-2.f * v[0]); o[1] = f2bf(-2.f * v[1]);
    o[2] = f2bf(-2.f * v[2]); o[3] = f2bf(-2.f * v[3]);

    const int j    = t >> 1;       // 8-elem chunk index within row (k/8)
    const int ks   = j >> 1;
    const int hi   = j & 1;
    const int half = t & 1;
    const int nj   = c >> 5;
    const int l31  = c & 31;
    *(bf16x4*)&wsb[(((nj * 17 + ks) * 64 + hi * 32 + l31) << 3) + half * 4] = o;

    float s = v[0]*v[0] + v[1]*v[1] + v[2]*v[2] + v[3]*v[3];   // raw |c|^2
    s += __shfl_xor(s, 1);  s += __shfl_xor(s, 2);  s += __shfl_xor(s, 4);
    s += __shfl_xor(s, 8);  s += __shfl_xor(s, 16); s += __shfl_xor(s, 32);
    if (t == 0) {
        float e = 1.f + s;
        short h = f2bf(e);  float e1 = e - bf2f(h);
        short m = f2bf(e1); float e2 = e1 - bf2f(m);
        short l = f2bf(e2);
        u32x4 a;
        a[0] = (unsigned)(unsigned short)h | ((unsigned)(unsigned short)m << 16);
        a[1] = (unsigned)(unsigned short)l;
        a[2] = 0u; a[3] = 0u;
        *(u32x4*)&wsb[((nj * 17 + 16) * 64 + l31) * 8] = a;         // k 256..263
        u32x4 z = {0u, 0u, 0u, 0u};
        *(u32x4*)&wsb[((nj * 17 + 16) * 64 + 32 + l31) * 8] = z;    // k 264..271
    }
}

// ---------------- Main kernel ----------------
__global__ __launch_bounds__(512, 6)
void cluster_q_main(const float* __restrict__ ctx,
                    const short* __restrict__ wsb,
                    float* __restrict__ out) {
    __shared__ short Af[2][8 * 64 * 8];     // 2 chunks x 8 KiB: [j=k/8][row][8]
    __shared__ float x2row[64];             // per-row |x|^2
    __shared__ float rowsum2[8][2][64];     // per-(wave,hi,row) q half-sums

    const int t    = threadIdx.x;
    const int lane = t & 63;
    const int w    = t >> 6;             // wave = col-eighth 0..7
    const int l31  = lane & 31;
    const int hi   = lane >> 5;
    const size_t row0 = (size_t)blockIdx.x * BM;

    // staging: thread t owns row srow, k-octet soct of every chunk
    const int srow = t >> 3;             // 0..63
    const int soct = t & 7;              // 8 consecutive floats
    const float* src = ctx + (row0 + (size_t)srow) * DD + soct * 8;

    // cluster fragment base: this wave's col-tile nj = w (17 frags)
    const short* bl = wsb + (size_t)(w * 17) * 512 + lane * 8;

    f32x4 ua[2], ub[2];
    // prologue: issue chunks 0 and 1
    ua[0] = ld4(src);        ub[0] = ld4(src + 4);
    ua[1] = ld4(src + 64);   ub[1] = ld4(src + 68);

    float xs = 0.f;

    // convert chunk 0 -> Af[0]
    {
        f32x4 a0 = ua[0], a1 = ub[0];
        u32x4 o;
        o[0] = cvtpk(a0[0], a0[1]); o[1] = cvtpk(a0[2], a0[3]);
        o[2] = cvtpk(a1[0], a1[1]); o[3] = cvtpk(a1[2], a1[3]);
        xs += a0[0]*a0[0] + a0[1]*a0[1] + a0[2]*a0[2] + a0[3]*a0[3]
            + a1[0]*a1[0] + a1[1]*a1[1] + a1[2]*a1[2] + a1[3]*a1[3];
        *(u32x4*)&Af[0][(soct * 64 + srow) * 8] = o;
    }
    __syncthreads();

    f32x16 acc0 = (f32x16)0.f, acc1 = (f32x16)0.f;

    // B (clusters): ping-pong, distance 1 (L2-hot)
    bf16x8 bs[2];
    bs[0] = *(const bf16x8*)(bl);                       // gs = 0

    // A (context) frags: ping-pong from LDS; s=0 of chunk 0 (j = hi)
    bf16x8 afA0 = *(const bf16x8*)&Af[0][(hi * 64 + l31) * 8];
    bf16x8 afA1 = *(const bf16x8*)&Af[0][(hi * 64 + 32 + l31) * 8];
    bf16x8 afB0, afB1;

#pragma unroll
    for (int kc = 0; kc < 4; ++kc) {
        const int buf = kc & 1;
        const short* AfC = &Af[buf][0];
        const short* AfN = &Af[buf ^ 1][0];

        // issue chunk kc+2 global loads (slot parity (kc+2)&1 == buf)
        if (kc < 2) {
            ua[buf] = ld4(src + (kc + 2) * 64);
            ub[buf] = ld4(src + (kc + 2) * 64 + 4);
        }

#pragma unroll
        for (int s = 0; s < 4; ++s) {
            const int gs = kc * 4 + s;

            // B prefetch for next global step
            if (gs < 15)
                bs[(gs + 1) & 1] = *(const bf16x8*)(bl + (gs + 1) * 512);

            // A prefetch for next step within this chunk
            if (s < 3) {
                const int jn = (s + 1) * 2 + hi;
                bf16x8 v0 = *(const bf16x8*)&AfC[(jn * 64 + l31) * 8];
                bf16x8 v1 = *(const bf16x8*)&AfC[(jn * 64 + 32 + l31) * 8];
                if (s & 1) { afA0 = v0; afA1 = v1; }
                else       { afB0 = v0; afB1 = v1; }
            }

            const bf16x8 a0 = (s & 1) ? afB0 : afA0;
            const bf16x8 a1 = (s & 1) ? afB1 : afA1;
            acc0 = __builtin_amdgcn_mfma_f32_32x32x16_bf16(bs[gs & 1], a0, acc0, 0, 0, 0);
            acc1 = __builtin_amdgcn_mfma_f32_32x32x16_bf16(bs[gs & 1], a1, acc1, 0, 0, 0);

            // convert chunk kc+1 between steps 1 and 2 (loads issued one
            // chunk ago; ds_write latency hides under s=2,3)
            if (s == 1 && kc < 3) {
                f32x4 c0 = ua[buf ^ 1], c1 = ub[buf ^ 1];
                u32x4 o;
                o[0] = cvtpk(c0[0], c0[1]); o[1] = cvtpk(c0[2], c0[3]);
                o[2] = cvtpk(c1[0], c1[1]); o[3] = cvtpk(c1[2], c1[3]);
                xs += c0[0]*c0[0] + c0[1]*c0[1] + c0[2]*c0[2] + c0[3]*c0[3]
                    + c1[0]*c1[0] + c1[1]*c1[1] + c1[2]*c1[2] + c1[3]*c1[3];
                *(u32x4*)&Af[buf ^ 1][(soct * 64 + srow) * 8] = o;
                if (kc == 2) {
                    // |x|^2 totals: reduce over the row's 8 k-octet lanes
                    float xr = xs;
                    xr += __shfl_xor(xr, 1);
                    xr += __shfl_xor(xr, 2);
                    xr += __shfl_xor(xr, 4);
                    if ((lane & 7) == 0) x2row[srow] = xr;
                }
            }
        }

        if (kc < 3) {
            __syncthreads();
            // s=0 frags of next chunk (j = hi)
            afA0 = *(const bf16x8*)&AfN[(hi * 64 + l31) * 8];
            afA1 = *(const bf16x8*)&AfN[(hi * 64 + 32 + l31) * 8];
        }
    }

    // aug step: adds (1 + |c|^2) per cluster -> acc = 1 + c2 - 2xc
    {
        bf16x8 bsa = *(const bf16x8*)(bl + 16 * 512);
        bf16x8 ctx_aug = (bf16x8)0;
        if (hi == 0) {
            ctx_aug[0] = (short)0x3F80; ctx_aug[1] = (short)0x3F80;
            ctx_aug[2] = (short)0x3F80;
        }
        acc0 = __builtin_amdgcn_mfma_f32_32x32x16_bf16(bsa, ctx_aug, acc0, 0, 0, 0);
        acc1 = __builtin_amdgcn_mfma_f32_32x32x16_bf16(bsa, ctx_aug, acc1, 0, 0, 0);
    }

    // ---- pass 1: q = rcp(acc + x2lane), in-lane half-row sums ----
    const float x2A = x2row[l31];          // ctx row l31   (acc0 columns)
    const float x2B = x2row[32 + l31];     // ctx row 32+l31 (acc1 columns)
    float s0 = 0.f, s1 = 0.f;
#pragma unroll
    for (int r = 0; r < 16; ++r) {
        acc0[r] = frcp(acc0[r] + x2A); s0 += acc0[r];
        acc1[r] = frcp(acc1[r] + x2B); s1 += acc1[r];
    }
    rowsum2[w][hi][l31]      = s0;
    rowsum2[w][hi][32 + l31] = s1;
    __syncthreads();

    // ---- pass 2: row totals, normalize, dwordx4 stores ----
    float t0 = 0.f, t1 = 0.f;
#pragma unroll
    for (int q = 0; q < 8; ++q) {
        t0 += rowsum2[q][0][l31]      + rowsum2[q][1][l31];
        t1 += rowsum2[q][0][32 + l31] + rowsum2[q][1][32 + l31];
    }
    const float inv0 = frcp(t0);
    const float inv1 = frcp(t1);

    float* op0 = out + (row0 + (size_t)l31) * KC        + w * 32 + 4 * hi;
    float* op1 = out + (row0 + (size_t)(32 + l31)) * KC + w * 32 + 4 * hi;
#pragma unroll
    for (int i = 0; i < 4; ++i) {
        f32x4 v0, v1;
#pragma unroll
        for (int j = 0; j < 4; ++j) {
            v0[j] = acc0[4 * i + j] * inv0;   // cluster col = 8i + 4hi + j
            v1[j] = acc1[4 * i + j] * inv1;
        }
        *(f32x4*)(op0 + 8 * i) = v0;
        *(f32x4*)(op1 + 8 * i) = v1;
    }
}

extern "C" void kernel_launch(void* const* d_in, const int* in_sizes, int n_in,
                              void* d_out, int out_size, void* d_ws, size_t ws_size,
                              hipStream_t stream) {
    const float* ctx  = (const float*)d_in[0];
    const float* clus = (const float*)d_in[1];
    float* out = (float*)d_out;

    short* wsb = (short*)d_ws;     // cluster fragment image (8*17 KiB = 136 KiB)

    const int nrows = in_sizes[0] / DD;                      // 524288
    const int grid  = nrows / BM;                            // 8192

    hipLaunchKernelGGL(prep_clusters, dim3(KC), dim3(64), 0, stream, clus, wsb);
    hipLaunchKernelGGL(cluster_q_main, dim3(grid), dim3(512), 0, stream,
                       ctx, wsb, out);
}